// Round 17
// baseline (255.529 us; speedup 1.0000x reference)
//
#include <hip/hip_runtime.h>

namespace {

constexpr int L = 10000;   // links
constexpr int F = 8;       // input features
constexpr int H = 64;      // hidden size

typedef __bf16 bf16x8 __attribute__((ext_vector_type(8)));
typedef float  f32x4  __attribute__((ext_vector_type(4)));

__device__ __forceinline__ float fsigmoid(float x) {
    return 1.0f / (1.0f + __expf(-x));
}
__device__ __forceinline__ float ftanh(float x) {
    return 2.0f / (1.0f + __expf(-2.0f * x)) - 1.0f;
}
__device__ __forceinline__ unsigned pack2(float lo, float hi) {
    __bf16 l = (__bf16)lo, h = (__bf16)hi;
    return (unsigned)__builtin_bit_cast(unsigned short, l) |
           ((unsigned)__builtin_bit_cast(unsigned short, h) << 16);
}
__device__ __forceinline__ float unbf(unsigned short u) {
    return (float)__builtin_bit_cast(__bf16, u);
}

// Async global->LDS, 16B/lane; queue lives in vmcnt (regalloc-proof).
__device__ __forceinline__ void gload_lds16(const float* g, float* l) {
    __builtin_amdgcn_global_load_lds(
        (const __attribute__((address_space(1))) void*)g,
        (__attribute__((address_space(3))) void*)l, 16, 0, 0);
}

// ---------------- workspace layout (bytes) ----------------
constexpr size_t PA_OFF  = 0;
constexpr size_t PB_OFF  = PA_OFF + (size_t)L * 4608;   //  46,080,000
constexpr size_t PNU_OFF = PB_OFF + (size_t)L * 1024;   //  56,320,000
constexpr size_t WS_NEED = PNU_OFF + (size_t)L * 8192;  // 138,240,000

// =====================================================================
// Pass 1: pack A-fragments + biases (at roofline since R11 -- unchanged).
// =====================================================================
__global__ __launch_bounds__(256)
void pre_pack(const float* __restrict__ hidden, const float* __restrict__ xin,
              const float* __restrict__ Brh, const float* __restrict__ Bri,
              const float* __restrict__ Buh, const float* __restrict__ Bui,
              const float* __restrict__ Bnh, const float* __restrict__ Bni,
              uint4* __restrict__ PA, float* __restrict__ PB)
{
    const int jt = blockIdx.x >> 2;
    const int quarter = blockIdx.x & 3;
    const int j0 = jt * 16;
    const int jl = threadIdx.x & 15;
    const int qs = threadIdx.x >> 4;
    const int j = j0 + jl;

    const int qlo = quarter * 88, qhi = qlo + 88;
    for (int q = qlo + qs; q < qhi; q += 16) {
        if (q < 256) {
            const int s = q >> 6, ql = q & 63;
            const int grp = ql >> 4, lc = ql & 15;
            const int m = s >> 1, ks = s & 1;
            const int b = m * 16 + lc;
            const int i0 = ks * 32 + grp * 8;
            const size_t base = ((size_t)b * H + i0) * L + j;
            float v[8];
#pragma unroll
            for (int e = 0; e < 8; ++e) v[e] = hidden[base + (size_t)e * L];
            uint4 w;
            w.x = pack2(v[0], v[1]); w.y = pack2(v[2], v[3]);
            w.z = pack2(v[4], v[5]); w.w = pack2(v[6], v[7]);
            PA[(size_t)j * 288 + q] = w;
        } else if (q < 288) {
            const int t = q - 256;
            const int m = t >> 4, lc = t & 15;
            const int b = m * 16 + lc;
            float v[8];
#pragma unroll
            for (int e = 0; e < 8; ++e) v[e] = xin[((size_t)b * F + e) * L + j];
            uint4 w;
            w.x = pack2(v[0], v[1]); w.y = pack2(v[2], v[3]);
            w.z = pack2(v[4], v[5]); w.w = pack2(v[6], v[7]);
            PA[(size_t)j * 288 + q] = w;
        } else {
            const int w0 = (q - 288) * 4;
            const int g = w0 >> 6, k0 = w0 & 63;
            float v[4];
#pragma unroll
            for (int e = 0; e < 4; ++e) {
                const size_t o = (size_t)(k0 + e) * L + j;
                if (g == 0)      v[e] = Brh[o] + Bri[o];
                else if (g == 1) v[e] = Buh[o] + Bui[o];
                else if (g == 2) v[e] = Bnh[o];
                else             v[e] = Bni[o];
            }
            *(f32x4*)&PB[(size_t)j * 256 + w0] = (f32x4){v[0], v[1], v[2], v[3]};
        }
    }
}

// =====================================================================
// Main: 2 links per 512-thread block, counted-vmcnt pipeline (T4):
//   issue A-stream(7 gload + 7 vload per wave) | fence |
//   issue B-stream(14)                         |
//   vmcnt(14)  -> A's 14 oldest done, B's 14 still IN FLIGHT
//   s_barrier  -> compute A (B streams through it), store A (+1 vmem)
//   vmcnt(1)   -> B's 14 done (A's store may remain)
//   s_barrier  -> compute B.
// vmcnt retires oldest-first (guide m135); counts are exact because each
// wave issues a fixed 7+7 ops per link (chunks 54/55 wrap to dup chunks
// 0/1 -- same-data double LDS write, benign). Raw s_barrier (NOT
// __syncthreads -- that drains vmcnt(0) and kills the overlap, the
// R15/R16 lesson) + sched_barrier(0) per guide rule #18.
// =====================================================================
constexpr int H_GATE  = 16 * 260;                 // 4160 words per hidden gate
constexpr int OFF_WI  = 3 * H_GATE;               // 12480
constexpr int I_GATE  = 2 * 260;                  // 520 words per input gate
constexpr int M_LDS   = OFF_WI + 3 * I_GATE;      // 14040 words = 54.8 KB

struct AStage {
    uint4 pah[2];   // A-frags for this wave's m (ks=0,1)
    uint4 pai;      // aI raw (grp0 content)
    float bi[4];    // biases for this wave's col
};

// exactly 7 gload_lds per wave (uniform -> vmcnt counts are constant)
__device__ __forceinline__ void stage_async7(
    int j, int w8, int lane,
    const float* __restrict__ Wrh, const float* __restrict__ Wuh,
    const float* __restrict__ Wnh, const float* __restrict__ Wri,
    const float* __restrict__ Wui, const float* __restrict__ Wni,
    float* __restrict__ dst)
{
    const float* WH0 = Wrh + (size_t)j * H * H;
    const float* WH1 = Wuh + (size_t)j * H * H;
    const float* WH2 = Wnh + (size_t)j * H * H;
    const float* WI0 = Wri + (size_t)j * F * H;
    const float* WI1 = Wui + (size_t)j * F * H;
    const float* WI2 = Wni + (size_t)j * F * H;
#pragma unroll
    for (int s = 0; s < 7; ++s) {
        int c = w8 + 8 * s;
        if (c >= 54) c -= 54;      // waves 6,7 slot 6: dup chunks 0,1 (benign)
        if (c < 48) {
            const int g = c >> 4, idx = c & 15;
            const float* src = (g == 0 ? WH0 : (g == 1 ? WH1 : WH2))
                               + idx * 256 + lane * 4;
            gload_lds16(src, &dst[g * H_GATE + idx * 260]);
        } else {
            const int c2 = c - 48;
            const int g = c2 >> 1, idx = c2 & 1;
            const float* src = (g == 0 ? WI0 : (g == 1 ? WI1 : WI2))
                               + idx * 256 + lane * 4;
            gload_lds16(src, &dst[OFF_WI + g * I_GATE + idx * 260]);
        }
    }
}

// exactly 7 vector loads per wave (2 pah + 1 pai + 4 bias dwords)
__device__ __forceinline__ void load_astage(
    int j, int m, int lane, int lc, int col,
    const uint4* __restrict__ PA, const float* __restrict__ PB, AStage& S)
{
    const uint4* pa = PA + (size_t)j * 288;
#pragma unroll
    for (int ks = 0; ks < 2; ++ks)
        S.pah[ks] = pa[(m * 2 + ks) * 64 + lane];
    S.pai = pa[256 + m * 16 + lc];
    const float* pb = PB + (size_t)j * 256;
#pragma unroll
    for (int g = 0; g < 4; ++g) S.bi[g] = pb[g * 64 + col];
}

// one PNU store per thread per link (counts as 1 vmem op)
__device__ __forceinline__ void compute_store(
    const float* __restrict__ sW, const AStage& S,
    int j, int n, int m, int lane, int grp, int col,
    uint4* __restrict__ PNU)
{
    const bf16x8 a0 = __builtin_bit_cast(bf16x8, S.pah[0]);
    const bf16x8 a1 = __builtin_bit_cast(bf16x8, S.pah[1]);
    const uint4 z = {0u, 0u, 0u, 0u};
    const bf16x8 ai = __builtin_bit_cast(bf16x8, (grp == 0) ? S.pai : z);

    auto rdH = [&](int g, int ks) -> bf16x8 {
        bf16x8 r;
#pragma unroll
        for (int e = 0; e < 8; ++e) {
            const int row = ks * 32 + grp * 8 + e;
            r[e] = (__bf16)sW[g * H_GATE + (row >> 2) * 260 + (row & 3) * 64 + col];
        }
        return r;
    };
    auto rdI = [&](int g) -> bf16x8 {
        bf16x8 r;
#pragma unroll
        for (int e = 0; e < 8; ++e)
            r[e] = (__bf16)sW[OFF_WI + g * I_GATE + (e >> 2) * 260 + (e & 3) * 64 + col];
        return r;
    };

    f32x4 accR  = (f32x4){0.f, 0.f, 0.f, 0.f};
    f32x4 accU  = (f32x4){0.f, 0.f, 0.f, 0.f};
    f32x4 accN  = (f32x4){0.f, 0.f, 0.f, 0.f};
    f32x4 accNI = (f32x4){0.f, 0.f, 0.f, 0.f};

    {
        const bf16x8 f0 = rdH(0, 0), f1 = rdH(0, 1), fi = rdI(0);
        accR = __builtin_amdgcn_mfma_f32_16x16x32_bf16(a0, f0, accR, 0, 0, 0);
        accR = __builtin_amdgcn_mfma_f32_16x16x32_bf16(a1, f1, accR, 0, 0, 0);
        accR = __builtin_amdgcn_mfma_f32_16x16x32_bf16(ai, fi, accR, 0, 0, 0);
    }
    {
        const bf16x8 f0 = rdH(1, 0), f1 = rdH(1, 1), fi = rdI(1);
        accU = __builtin_amdgcn_mfma_f32_16x16x32_bf16(a0, f0, accU, 0, 0, 0);
        accU = __builtin_amdgcn_mfma_f32_16x16x32_bf16(a1, f1, accU, 0, 0, 0);
        accU = __builtin_amdgcn_mfma_f32_16x16x32_bf16(ai, fi, accU, 0, 0, 0);
    }
    {
        const bf16x8 f0 = rdH(2, 0), f1 = rdH(2, 1), fi = rdI(2);
        accN = __builtin_amdgcn_mfma_f32_16x16x32_bf16(a0, f0, accN, 0, 0, 0);
        accN = __builtin_amdgcn_mfma_f32_16x16x32_bf16(a1, f1, accN, 0, 0, 0);
        accNI = __builtin_amdgcn_mfma_f32_16x16x32_bf16(ai, fi, accNI, 0, 0, 0);
    }

    float nv4[4], uv4[4];
#pragma unroll
    for (int rr = 0; rr < 4; ++rr) {
        const float rv = fsigmoid(accR[rr] + S.bi[0]);
        uv4[rr] = fsigmoid(accU[rr] + S.bi[1]);
        nv4[rr] = ftanh(rv * (accN[rr] + S.bi[2]) + accNI[rr] + S.bi[3]);
    }
    uint4 o;
    o.x = pack2(nv4[0], nv4[1]); o.y = pack2(nv4[2], nv4[3]);
    o.z = pack2(uv4[0], uv4[1]); o.w = pack2(uv4[2], uv4[3]);
    PNU[(size_t)j * 512 + (n * 2 + m) * 64 + lane] = o;
}

__global__ __launch_bounds__(512)
void gcrnn_main(const uint4* __restrict__ PA, const float* __restrict__ PB,
                const float* __restrict__ Wrh, const float* __restrict__ Wuh,
                const float* __restrict__ Wnh, const float* __restrict__ Wri,
                const float* __restrict__ Wui, const float* __restrict__ Wni,
                uint4* __restrict__ PNU)
{
    const int j0 = blockIdx.x * 2;

    __shared__ float sL[2 * M_LDS];   // 109.7 KB: A-buffer + B-buffer

    const int tb   = threadIdx.x;
    const int lane = tb & 63;
    const int w8   = tb >> 6;          // 0..7
    const int n    = w8 & 3;
    const int m    = w8 >> 2;
    const int lc   = lane & 15;
    const int grp  = lane >> 4;
    const int col  = n * 16 + lc;

    AStage SA, SB;

    // ---- region A: 7 gload_lds + 7 vloads per wave ----
    stage_async7(j0, w8, lane, Wrh, Wuh, Wnh, Wri, Wui, Wni, &sL[0]);
    load_astage(j0, m, lane, lc, col, PA, PB, SA);
    asm volatile("" ::: "memory");   // compiler fence: A group stays oldest

    // ---- region B: 14 more vmem ops ----
    stage_async7(j0 + 1, w8, lane, Wrh, Wuh, Wnh, Wri, Wui, Wni, &sL[M_LDS]);
    load_astage(j0 + 1, m, lane, lc, col, PA, PB, SB);

    // wait for A's 14 oldest; B's 14 remain in flight through compute A
    asm volatile("s_waitcnt vmcnt(14)" ::: "memory");
    __builtin_amdgcn_s_barrier();
    __builtin_amdgcn_sched_barrier(0);

    compute_store(&sL[0], SA, j0, n, m, lane, grp, col, PNU);   // +1 store

    // wait for B's loads (A's store, the newest op, may stay outstanding)
    asm volatile("s_waitcnt vmcnt(1)" ::: "memory");
    __builtin_amdgcn_s_barrier();
    __builtin_amdgcn_sched_barrier(0);

    compute_store(&sL[M_LDS], SB, j0 + 1, n, m, lane, grp, col, PNU);
}

// =====================================================================
// Pass 3: blend + transpose back (at roofline -- unchanged).
// =====================================================================
__global__ __launch_bounds__(256)
void post_blend(const uint4* __restrict__ PNU,
                const float* __restrict__ hidden, float* __restrict__ out)
{
    const int jt = blockIdx.x >> 2;
    const int quarter = blockIdx.x & 3;
    const int j0 = jt * 16;
    const int jl = threadIdx.x & 15;
    const int qs = threadIdx.x >> 4;
    const int j = j0 + jl;

    const int qlo = quarter * 128, qhi = qlo + 128;
    for (int q = qlo + qs; q < qhi; q += 16) {
        const int sp = q >> 6, lane = q & 63;
        const int n = sp >> 1, m = sp & 1;
        const int grp = lane >> 4, lc = lane & 15;
        const int k = n * 16 + lc;
        const int b0 = m * 16 + grp * 4;

        const uint4 pp = PNU[(size_t)j * 512 + q];
        float nn[4], u[4];
        nn[0] = unbf((unsigned short)(pp.x & 0xffff));
        nn[1] = unbf((unsigned short)(pp.x >> 16));
        nn[2] = unbf((unsigned short)(pp.y & 0xffff));
        nn[3] = unbf((unsigned short)(pp.y >> 16));
        u[0]  = unbf((unsigned short)(pp.z & 0xffff));
        u[1]  = unbf((unsigned short)(pp.z >> 16));
        u[2]  = unbf((unsigned short)(pp.w & 0xffff));
        u[3]  = unbf((unsigned short)(pp.w >> 16));
#pragma unroll
        for (int rr = 0; rr < 4; ++rr) {
            const size_t o = ((size_t)(b0 + rr) * H + k) * L + j;
            out[o] = (1.0f - u[rr]) * nn[rr] + u[rr] * hidden[o];
        }
    }
}

// =====================================================================
// Fallback (R9 kernel): used only if ws_size < WS_NEED.
// =====================================================================
constexpr int WROW     = 68;
constexpr int W_GATE   = 32 * WROW;                // 2176 words
constexpr int OFF_WIN  = 3 * W_GATE;               // 6528
constexpr int WIN_GATE = 4 * WROW;                 // 272
constexpr int FB_LDS0  = OFF_WIN + 3 * WIN_GATE;   // 7344
constexpr int FB_OFF_XH    = FB_LDS0;
constexpr int FB_LDS_WORDS = FB_OFF_XH + 64 * 33;  // 9456 words

__global__ __launch_bounds__(256, 4)
void gcrnn_fallback(const float* __restrict__ hidden, const float* __restrict__ xin,
                    const float* __restrict__ Wrh, const float* __restrict__ Brh,
                    const float* __restrict__ Wri, const float* __restrict__ Bri,
                    const float* __restrict__ Wuh, const float* __restrict__ Buh,
                    const float* __restrict__ Wui, const float* __restrict__ Bui,
                    const float* __restrict__ Wnh, const float* __restrict__ Bnh,
                    const float* __restrict__ Wni, const float* __restrict__ Bni,
                    float* __restrict__ out)
{
    const int orig = blockIdx.x;
    const int j = (orig & 7) * (L / 8) + (orig >> 3);

    __shared__ float sL[FB_LDS_WORDS];
    unsigned* sLu = (unsigned*)sL;
    const int tb = threadIdx.x;

    {
        const int pr = tb >> 4;
        const int c0 = (tb & 15) * 4;
        const float* Wg[3] = {Wrh + (size_t)j * H * H, Wuh + (size_t)j * H * H,
                              Wnh + (size_t)j * H * H};
#pragma unroll
        for (int g = 0; g < 3; ++g) {
#pragma unroll
            for (int it = 0; it < 2; ++it) {
                const int p = it * 16 + pr;
                const f32x4 a = *(const f32x4*)(Wg[g] + (size_t)(2 * p) * H + c0);
                const f32x4 b = *(const f32x4*)(Wg[g] + (size_t)(2 * p + 1) * H + c0);
                uint4 w;
                w.x = pack2(a[0], b[0]); w.y = pack2(a[1], b[1]);
                w.z = pack2(a[2], b[2]); w.w = pack2(a[3], b[3]);
                *(uint4*)&sLu[g * W_GATE + p * WROW + c0] = w;
            }
        }
        if (tb < 64) {
            const int p = tb >> 4;
            const int ci = (tb & 15) * 4;
            const float* Wig[3] = {Wri + (size_t)j * F * H, Wui + (size_t)j * F * H,
                                   Wni + (size_t)j * F * H};
#pragma unroll
            for (int g = 0; g < 3; ++g) {
                const f32x4 a = *(const f32x4*)(Wig[g] + (size_t)(2 * p) * H + ci);
                const f32x4 b = *(const f32x4*)(Wig[g] + (size_t)(2 * p + 1) * H + ci);
                uint4 w;
                w.x = pack2(a[0], b[0]); w.y = pack2(a[1], b[1]);
                w.z = pack2(a[2], b[2]); w.w = pack2(a[3], b[3]);
                *(uint4*)&sLu[OFF_WIN + g * WIN_GATE + p * WROW + ci] = w;
            }
        }
#pragma unroll
        for (int it = 0; it < 8; ++it) {
            const int idx = tb + 256 * it;
            const int b = idx & 31, i = idx >> 5;
            sL[FB_OFF_XH + i * 33 + b] = hidden[(size_t)(b * H + i) * L + j];
        }
    }
    __syncthreads();

    const int lane = tb & 63;
    const int n    = tb >> 6;
    const int lc   = lane & 15;
    const int grp  = lane >> 4;
    const int col  = n * 16 + lc;

    bf16x8 aH[2][2], aI[2];
#pragma unroll
    for (int m = 0; m < 2; ++m) {
        const int b_ = m * 16 + lc;
#pragma unroll
        for (int ks = 0; ks < 2; ++ks)
#pragma unroll
            for (int e = 0; e < 8; ++e)
                aH[m][ks][e] = (__bf16)sL[FB_OFF_XH + (ks * 32 + grp * 8 + e) * 33 + b_];
        const size_t ibase = (size_t)b_ * F * L + j;
#pragma unroll
        for (int e = 0; e < 8; ++e) {
            const float v = (grp == 0) ? xin[ibase + (size_t)e * L] : 0.0f;
            aI[m][e] = (__bf16)v;
        }
    }
    __syncthreads();

    const size_t ko = (size_t)col * L + j;
    const float biR  = Brh[ko] + Bri[ko];
    const float biU  = Buh[ko] + Bui[ko];
    const float biNH = Bnh[ko];
    const float biNI = Bni[ko];

    auto rdH = [&](int g, int ks) -> bf16x8 {
        uint4 t;
        t.x = sLu[g * W_GATE + (ks * 16 + grp * 4 + 0) * WROW + col];
        t.y = sLu[g * W_GATE + (ks * 16 + grp * 4 + 1) * WROW + col];
        t.z = sLu[g * W_GATE + (ks * 16 + grp * 4 + 2) * WROW + col];
        t.w = sLu[g * W_GATE + (ks * 16 + grp * 4 + 3) * WROW + col];
        return __builtin_bit_cast(bf16x8, t);
    };
    auto rdI = [&](int g) -> bf16x8 {
        uint4 t;
        t.x = (grp == 0) ? sLu[OFF_WIN + g * WIN_GATE + 0 * WROW + col] : 0u;
        t.y = (grp == 0) ? sLu[OFF_WIN + g * WIN_GATE + 1 * WROW + col] : 0u;
        t.z = (grp == 0) ? sLu[OFF_WIN + g * WIN_GATE + 2 * WROW + col] : 0u;
        t.w = (grp == 0) ? sLu[OFF_WIN + g * WIN_GATE + 3 * WROW + col] : 0u;
        return __builtin_bit_cast(bf16x8, t);
    };

    const bf16x8 fR0 = rdH(0, 0), fR1 = rdH(0, 1);
    const bf16x8 fU0 = rdH(1, 0), fU1 = rdH(1, 1);
    const bf16x8 fN0 = rdH(2, 0), fN1 = rdH(2, 1);
    const bf16x8 fRI = rdI(0), fUI = rdI(1), fNI = rdI(2);

    f32x4 accR[2], accU[2], accN[2], accNI[2];
#pragma unroll
    for (int m = 0; m < 2; ++m) {
        accR[m]  = (f32x4){0.f, 0.f, 0.f, 0.f};
        accU[m]  = (f32x4){0.f, 0.f, 0.f, 0.f};
        accN[m]  = (f32x4){0.f, 0.f, 0.f, 0.f};
        accNI[m] = (f32x4){0.f, 0.f, 0.f, 0.f};
        accR[m] = __builtin_amdgcn_mfma_f32_16x16x32_bf16(aH[m][0], fR0, accR[m], 0, 0, 0);
        accR[m] = __builtin_amdgcn_mfma_f32_16x16x32_bf16(aH[m][1], fR1, accR[m], 0, 0, 0);
        accU[m] = __builtin_amdgcn_mfma_f32_16x16x32_bf16(aH[m][0], fU0, accU[m], 0, 0, 0);
        accU[m] = __builtin_amdgcn_mfma_f32_16x16x32_bf16(aH[m][1], fU1, accU[m], 0, 0, 0);
        accN[m] = __builtin_amdgcn_mfma_f32_16x16x32_bf16(aH[m][0], fN0, accN[m], 0, 0, 0);
        accN[m] = __builtin_amdgcn_mfma_f32_16x16x32_bf16(aH[m][1], fN1, accN[m], 0, 0, 0);
        accR[m]  = __builtin_amdgcn_mfma_f32_16x16x32_bf16(aI[m], fRI, accR[m], 0, 0, 0);
        accU[m]  = __builtin_amdgcn_mfma_f32_16x16x32_bf16(aI[m], fUI, accU[m], 0, 0, 0);
        accNI[m] = __builtin_amdgcn_mfma_f32_16x16x32_bf16(aI[m], fNI, accNI[m], 0, 0, 0);
    }

#pragma unroll
    for (int m = 0; m < 2; ++m)
#pragma unroll
        for (int rr = 0; rr < 4; ++rr) {
            const int b_ = m * 16 + grp * 4 + rr;
            const int w = FB_OFF_XH + col * 33 + b_;
            const float h = sL[w];
            const float rv = fsigmoid(accR[m][rr] + biR);
            const float uv = fsigmoid(accU[m][rr] + biU);
            const float nv = ftanh(rv * (accN[m][rr] + biNH) + accNI[m][rr] + biNI);
            sL[w] = (1.0f - uv) * nv + uv * h;
        }
    __syncthreads();

#pragma unroll
    for (int it = 0; it < 8; ++it) {
        const int idx = tb + 256 * it;
        const int b = idx & 31, k = idx >> 5;
        out[(size_t)(b * H + k) * L + j] = sL[FB_OFF_XH + k * 33 + b];
    }
}

} // namespace

extern "C" void kernel_launch(void* const* d_in, const int* in_sizes, int n_in,
                              void* d_out, int out_size, void* d_ws, size_t ws_size,
                              hipStream_t stream) {
    const float* hidden = (const float*)d_in[0];
    const float* xin    = (const float*)d_in[1];
    const float* Wrh    = (const float*)d_in[2];
    const float* Brh    = (const float*)d_in[3];
    const float* Wri    = (const float*)d_in[4];
    const float* Bri    = (const float*)d_in[5];
    const float* Wuh    = (const float*)d_in[6];
    const float* Buh    = (const float*)d_in[7];
    const float* Wui    = (const float*)d_in[8];
    const float* Bui    = (const float*)d_in[9];
    const float* Wnh    = (const float*)d_in[10];
    const float* Bnh    = (const float*)d_in[11];
    const float* Wni    = (const float*)d_in[12];
    const float* Bni    = (const float*)d_in[13];
    float* out = (float*)d_out;

    if (ws_size >= WS_NEED) {
        char* ws = (char*)d_ws;
        uint4* PA  = (uint4*)(ws + PA_OFF);
        float* PB  = (float*)(ws + PB_OFF);
        uint4* PNU = (uint4*)(ws + PNU_OFF);

        pre_pack<<<(L / 16) * 4, 256, 0, stream>>>(hidden, xin,
                                                   Brh, Bri, Buh, Bui, Bnh, Bni,
                                                   PA, PB);
        gcrnn_main<<<L / 2, 512, 0, stream>>>(PA, PB,
                                              Wrh, Wuh, Wnh, Wri, Wui, Wni,
                                              PNU);
        post_blend<<<(L / 16) * 4, 256, 0, stream>>>(PNU, hidden, out);
    } else {
        gcrnn_fallback<<<L, 256, 0, stream>>>(hidden, xin,
                                              Wrh, Brh, Wri, Bri,
                                              Wuh, Buh, Wui, Bui,
                                              Wnh, Bnh, Wni, Bni,
                                              out);
    }
}

// Round 18
// 238.284 us; speedup vs baseline: 1.0724x; 1.0724x over previous
//
#include <hip/hip_runtime.h>

namespace {

constexpr int L = 10000;   // links
constexpr int F = 8;       // input features
constexpr int H = 64;      // hidden size

typedef __bf16 bf16x8 __attribute__((ext_vector_type(8)));
typedef float  f32x4  __attribute__((ext_vector_type(4)));

__device__ __forceinline__ float fsigmoid(float x) {
    return 1.0f / (1.0f + __expf(-x));
}
__device__ __forceinline__ float ftanh(float x) {
    return 2.0f / (1.0f + __expf(-2.0f * x)) - 1.0f;
}
__device__ __forceinline__ unsigned pack2(float lo, float hi) {
    __bf16 l = (__bf16)lo, h = (__bf16)hi;
    return (unsigned)__builtin_bit_cast(unsigned short, l) |
           ((unsigned)__builtin_bit_cast(unsigned short, h) << 16);
}
__device__ __forceinline__ float unbf(unsigned short u) {
    return (float)__builtin_bit_cast(__bf16, u);
}

// ---------------- workspace layout (bytes) ----------------
// PA : per link 288 uint4 (4.5 KB): slots 0..255 = aH[m=s>>1][ks=s&1] in exact
//      MFMA lane order; slots 256..287 = aI densely packed (grp0 lanes only).
// PB : per link 256 f32 (1 KB) = [g=R,U,NH,NI][col] (R/U biases combined)
// PNU: per link 512 uint4 (8 KB) = {n01,n23,u01,u23} bf16-packed per (s,lane)
constexpr size_t PA_OFF  = 0;
constexpr size_t PB_OFF  = PA_OFF + (size_t)L * 4608;   //  46,080,000
constexpr size_t PNU_OFF = PB_OFF + (size_t)L * 1024;   //  56,320,000
constexpr size_t WS_NEED = PNU_OFF + (size_t)L * 8192;  // 138,240,000

// =====================================================================
// Pass 1: pack A-fragments + biases. (q x 16 j-inner lanes) map: every
// wave-level transaction covers full 64B lines.
// =====================================================================
__global__ __launch_bounds__(256)
void pre_pack(const float* __restrict__ hidden, const float* __restrict__ xin,
              const float* __restrict__ Brh, const float* __restrict__ Bri,
              const float* __restrict__ Buh, const float* __restrict__ Bui,
              const float* __restrict__ Bnh, const float* __restrict__ Bni,
              uint4* __restrict__ PA, float* __restrict__ PB)
{
    const int jt = blockIdx.x >> 2;        // j-tile of 16
    const int quarter = blockIdx.x & 3;
    const int j0 = jt * 16;
    const int jl = threadIdx.x & 15;
    const int qs = threadIdx.x >> 4;
    const int j = j0 + jl;

    const int qlo = quarter * 88, qhi = qlo + 88;   // 352 q-units total
    for (int q = qlo + qs; q < qhi; q += 16) {
        if (q < 256) {
            const int s = q >> 6, ql = q & 63;
            const int grp = ql >> 4, lc = ql & 15;
            const int m = s >> 1, ks = s & 1;
            const int b = m * 16 + lc;
            const int i0 = ks * 32 + grp * 8;
            const size_t base = ((size_t)b * H + i0) * L + j;
            float v[8];
#pragma unroll
            for (int e = 0; e < 8; ++e) v[e] = hidden[base + (size_t)e * L];
            uint4 w;
            w.x = pack2(v[0], v[1]); w.y = pack2(v[2], v[3]);
            w.z = pack2(v[4], v[5]); w.w = pack2(v[6], v[7]);
            PA[(size_t)j * 288 + q] = w;
        } else if (q < 288) {
            const int t = q - 256;
            const int m = t >> 4, lc = t & 15;
            const int b = m * 16 + lc;
            float v[8];
#pragma unroll
            for (int e = 0; e < 8; ++e) v[e] = xin[((size_t)b * F + e) * L + j];
            uint4 w;
            w.x = pack2(v[0], v[1]); w.y = pack2(v[2], v[3]);
            w.z = pack2(v[4], v[5]); w.w = pack2(v[6], v[7]);
            PA[(size_t)j * 288 + q] = w;
        } else {
            const int w0 = (q - 288) * 4;
            const int g = w0 >> 6, k0 = w0 & 63;
            float v[4];
#pragma unroll
            for (int e = 0; e < 4; ++e) {
                const size_t o = (size_t)(k0 + e) * L + j;
                if (g == 0)      v[e] = Brh[o] + Bri[o];
                else if (g == 1) v[e] = Buh[o] + Bui[o];
                else if (g == 2) v[e] = Bnh[o];
                else             v[e] = Bni[o];
            }
            *(f32x4*)&PB[(size_t)j * 256 + w0] = (f32x4){v[0], v[1], v[2], v[3]};
        }
    }
}

// =====================================================================
// Main: one link per 256-thread block; wave n owns col-tile n.
// Staging is LOAD-ALL-THEN-PACK with no min-occupancy demand (best
// measured config, R12: 160 us main). R10-R17 swept eight schedule
// classes (VGPR queues, async gload_lds, dbuf pipelines, counted
// vmcnt); all pinned at 160-213 us -> schedule-invariant wall for this
// single-use weight-stream pattern.
// =====================================================================
constexpr int WROW     = 68;
constexpr int W_GATE   = 32 * WROW;                // 2176 words
constexpr int OFF_WIN  = 3 * W_GATE;               // 6528
constexpr int WIN_GATE = 4 * WROW;                 // 272
constexpr int LDS_WORDS = OFF_WIN + 3 * WIN_GATE;  // 7344 words = 29.4 KB

__global__ __launch_bounds__(256)
void gcrnn_main(const uint4* __restrict__ PA, const float* __restrict__ PB,
                const float* __restrict__ Wrh, const float* __restrict__ Wuh,
                const float* __restrict__ Wnh, const float* __restrict__ Wri,
                const float* __restrict__ Wui, const float* __restrict__ Wni,
                uint4* __restrict__ PNU)
{
    const int j = blockIdx.x;

    __shared__ float sL[LDS_WORDS];
    unsigned* sLu = (unsigned*)sL;

    const int tb = threadIdx.x;
    const int lane = tb & 63;
    const int n    = tb >> 6;
    const int lc   = lane & 15;
    const int grp  = lane >> 4;
    const int col  = n * 16 + lc;

    // ---- issue A-frag + bias loads first (latency hides under weight burst)
    const uint4* pa = PA + (size_t)j * 288;
    bf16x8 aH[2][2], aI[2];
#pragma unroll
    for (int m = 0; m < 2; ++m) {
#pragma unroll
        for (int ks = 0; ks < 2; ++ks)
            aH[m][ks] = __builtin_bit_cast(bf16x8, pa[(m * 2 + ks) * 64 + lane]);
        uint4 z = {0u, 0u, 0u, 0u};
        aI[m] = __builtin_bit_cast(bf16x8, (grp == 0) ? pa[256 + m * 16 + lc] : z);
    }
    const float* pb = PB + (size_t)j * 256;
    const float biR  = pb[col];
    const float biU  = pb[64 + col];
    const float biNH = pb[128 + col];
    const float biNI = pb[192 + col];

    // ---- weight staging: LOAD ALL into registers, THEN pack to LDS ----
    const int pr = tb >> 4;          // 0..15
    const int c0 = (tb & 15) * 4;    // col quad
    const float* WgH[3] = {Wrh + (size_t)j * H * H,
                           Wuh + (size_t)j * H * H,
                           Wnh + (size_t)j * H * H};
    f32x4 wa[6], wb[6];
#pragma unroll
    for (int g = 0; g < 3; ++g)
#pragma unroll
        for (int it = 0; it < 2; ++it) {
            const int p = it * 16 + pr;
            wa[g * 2 + it] = *(const f32x4*)(WgH[g] + (size_t)(2 * p) * H + c0);
            wb[g * 2 + it] = *(const f32x4*)(WgH[g] + (size_t)(2 * p + 1) * H + c0);
        }
    f32x4 ia[3], ib[3];
    const bool doI = (tb < 64);
    if (doI) {
        const int p = tb >> 4;            // 0..3
        const int ci = (tb & 15) * 4;
        const float* WgI[3] = {Wri + (size_t)j * F * H,
                               Wui + (size_t)j * F * H,
                               Wni + (size_t)j * F * H};
#pragma unroll
        for (int g = 0; g < 3; ++g) {
            ia[g] = *(const f32x4*)(WgI[g] + (size_t)(2 * p) * H + ci);
            ib[g] = *(const f32x4*)(WgI[g] + (size_t)(2 * p + 1) * H + ci);
        }
    }
    // pack + LDS write (loads drain progressively while packing)
#pragma unroll
    for (int gi = 0; gi < 6; ++gi) {
        const int g = gi >> 1;
        const int p = (gi & 1) * 16 + pr;
        uint4 w;
        w.x = pack2(wa[gi][0], wb[gi][0]);
        w.y = pack2(wa[gi][1], wb[gi][1]);
        w.z = pack2(wa[gi][2], wb[gi][2]);
        w.w = pack2(wa[gi][3], wb[gi][3]);
        *(uint4*)&sLu[g * W_GATE + p * WROW + c0] = w;
    }
    if (doI) {
        const int p = tb >> 4;
        const int ci = (tb & 15) * 4;
#pragma unroll
        for (int g = 0; g < 3; ++g) {
            uint4 w;
            w.x = pack2(ia[g][0], ib[g][0]);
            w.y = pack2(ia[g][1], ib[g][1]);
            w.z = pack2(ia[g][2], ib[g][2]);
            w.w = pack2(ia[g][3], ib[g][3]);
            *(uint4*)&sLu[OFF_WIN + g * WIN_GATE + p * WROW + ci] = w;
        }
    }
    __syncthreads();

    // ---- B-fragments from packed LDS ----
    auto rdH = [&](int g, int ks) -> bf16x8 {
        uint4 t;
        t.x = sLu[g * W_GATE + (ks * 16 + grp * 4 + 0) * WROW + col];
        t.y = sLu[g * W_GATE + (ks * 16 + grp * 4 + 1) * WROW + col];
        t.z = sLu[g * W_GATE + (ks * 16 + grp * 4 + 2) * WROW + col];
        t.w = sLu[g * W_GATE + (ks * 16 + grp * 4 + 3) * WROW + col];
        return __builtin_bit_cast(bf16x8, t);
    };
    auto rdI = [&](int g) -> bf16x8 {
        uint4 t;
        t.x = (grp == 0) ? sLu[OFF_WIN + g * WIN_GATE + 0 * WROW + col] : 0u;
        t.y = (grp == 0) ? sLu[OFF_WIN + g * WIN_GATE + 1 * WROW + col] : 0u;
        t.z = (grp == 0) ? sLu[OFF_WIN + g * WIN_GATE + 2 * WROW + col] : 0u;
        t.w = (grp == 0) ? sLu[OFF_WIN + g * WIN_GATE + 3 * WROW + col] : 0u;
        return __builtin_bit_cast(bf16x8, t);
    };

    const bf16x8 fR0 = rdH(0, 0), fR1 = rdH(0, 1);
    const bf16x8 fU0 = rdH(1, 0), fU1 = rdH(1, 1);
    const bf16x8 fN0 = rdH(2, 0), fN1 = rdH(2, 1);
    const bf16x8 fRI = rdI(0), fUI = rdI(1), fNI = rdI(2);

    f32x4 accR[2], accU[2], accN[2], accNI[2];
#pragma unroll
    for (int m = 0; m < 2; ++m) {
        accR[m]  = (f32x4){0.f, 0.f, 0.f, 0.f};
        accU[m]  = (f32x4){0.f, 0.f, 0.f, 0.f};
        accN[m]  = (f32x4){0.f, 0.f, 0.f, 0.f};
        accNI[m] = (f32x4){0.f, 0.f, 0.f, 0.f};
        accR[m] = __builtin_amdgcn_mfma_f32_16x16x32_bf16(aH[m][0], fR0, accR[m], 0, 0, 0);
        accR[m] = __builtin_amdgcn_mfma_f32_16x16x32_bf16(aH[m][1], fR1, accR[m], 0, 0, 0);
        accU[m] = __builtin_amdgcn_mfma_f32_16x16x32_bf16(aH[m][0], fU0, accU[m], 0, 0, 0);
        accU[m] = __builtin_amdgcn_mfma_f32_16x16x32_bf16(aH[m][1], fU1, accU[m], 0, 0, 0);
        accN[m] = __builtin_amdgcn_mfma_f32_16x16x32_bf16(aH[m][0], fN0, accN[m], 0, 0, 0);
        accN[m] = __builtin_amdgcn_mfma_f32_16x16x32_bf16(aH[m][1], fN1, accN[m], 0, 0, 0);
        accR[m]  = __builtin_amdgcn_mfma_f32_16x16x32_bf16(aI[m], fRI, accR[m], 0, 0, 0);
        accU[m]  = __builtin_amdgcn_mfma_f32_16x16x32_bf16(aI[m], fUI, accU[m], 0, 0, 0);
        accNI[m] = __builtin_amdgcn_mfma_f32_16x16x32_bf16(aI[m], fNI, accNI[m], 0, 0, 0);
    }

    // ---- epilogue: one packed bf16 uint4 store per m ----
#pragma unroll
    for (int m = 0; m < 2; ++m) {
        float nv4[4], uv4[4];
#pragma unroll
        for (int rr = 0; rr < 4; ++rr) {
            const float rv = fsigmoid(accR[m][rr] + biR);
            uv4[rr] = fsigmoid(accU[m][rr] + biU);
            nv4[rr] = ftanh(rv * (accN[m][rr] + biNH) + accNI[m][rr] + biNI);
        }
        uint4 o;
        o.x = pack2(nv4[0], nv4[1]); o.y = pack2(nv4[2], nv4[3]);
        o.z = pack2(uv4[0], uv4[1]); o.w = pack2(uv4[2], uv4[3]);
        PNU[(size_t)j * 512 + (n * 2 + m) * 64 + lane] = o;
    }
}

// =====================================================================
// Pass 3: blend + transpose back, (q x 16 j-inner) line-perfect map.
// =====================================================================
__global__ __launch_bounds__(256)
void post_blend(const uint4* __restrict__ PNU,
                const float* __restrict__ hidden, float* __restrict__ out)
{
    const int jt = blockIdx.x >> 2;
    const int quarter = blockIdx.x & 3;
    const int j0 = jt * 16;
    const int jl = threadIdx.x & 15;
    const int qs = threadIdx.x >> 4;
    const int j = j0 + jl;

    const int qlo = quarter * 128, qhi = qlo + 128;   // 512 q-units
    for (int q = qlo + qs; q < qhi; q += 16) {
        const int sp = q >> 6, lane = q & 63;
        const int n = sp >> 1, m = sp & 1;
        const int grp = lane >> 4, lc = lane & 15;
        const int k = n * 16 + lc;
        const int b0 = m * 16 + grp * 4;

        const uint4 pp = PNU[(size_t)j * 512 + q];
        float nn[4], u[4];
        nn[0] = unbf((unsigned short)(pp.x & 0xffff));
        nn[1] = unbf((unsigned short)(pp.x >> 16));
        nn[2] = unbf((unsigned short)(pp.y & 0xffff));
        nn[3] = unbf((unsigned short)(pp.y >> 16));
        u[0]  = unbf((unsigned short)(pp.z & 0xffff));
        u[1]  = unbf((unsigned short)(pp.z >> 16));
        u[2]  = unbf((unsigned short)(pp.w & 0xffff));
        u[3]  = unbf((unsigned short)(pp.w >> 16));
#pragma unroll
        for (int rr = 0; rr < 4; ++rr) {
            const size_t o = ((size_t)(b0 + rr) * H + k) * L + j;
            out[o] = (1.0f - u[rr]) * nn[rr] + u[rr] * hidden[o];
        }
    }
}

// =====================================================================
// Fallback (R9 kernel, 295 us): used only if ws_size < WS_NEED.
// =====================================================================
constexpr int FB_OFF_XH    = LDS_WORDS;             // 7344
constexpr int FB_LDS_WORDS = FB_OFF_XH + 64 * 33;   // 9456 words

__global__ __launch_bounds__(256, 4)
void gcrnn_fallback(const float* __restrict__ hidden, const float* __restrict__ xin,
                    const float* __restrict__ Wrh, const float* __restrict__ Brh,
                    const float* __restrict__ Wri, const float* __restrict__ Bri,
                    const float* __restrict__ Wuh, const float* __restrict__ Buh,
                    const float* __restrict__ Wui, const float* __restrict__ Bui,
                    const float* __restrict__ Wnh, const float* __restrict__ Bnh,
                    const float* __restrict__ Wni, const float* __restrict__ Bni,
                    float* __restrict__ out)
{
    const int orig = blockIdx.x;
    const int j = (orig & 7) * (L / 8) + (orig >> 3);

    __shared__ float sL[FB_LDS_WORDS];
    unsigned* sLu = (unsigned*)sL;
    const int tb = threadIdx.x;

    {
        const int pr = tb >> 4;
        const int c0 = (tb & 15) * 4;
        const float* Wg[3] = {Wrh + (size_t)j * H * H, Wuh + (size_t)j * H * H,
                              Wnh + (size_t)j * H * H};
#pragma unroll
        for (int g = 0; g < 3; ++g) {
#pragma unroll
            for (int it = 0; it < 2; ++it) {
                const int p = it * 16 + pr;
                const f32x4 a = *(const f32x4*)(Wg[g] + (size_t)(2 * p) * H + c0);
                const f32x4 b = *(const f32x4*)(Wg[g] + (size_t)(2 * p + 1) * H + c0);
                uint4 w;
                w.x = pack2(a[0], b[0]); w.y = pack2(a[1], b[1]);
                w.z = pack2(a[2], b[2]); w.w = pack2(a[3], b[3]);
                *(uint4*)&sLu[g * W_GATE + p * WROW + c0] = w;
            }
        }
        if (tb < 64) {
            const int p = tb >> 4;
            const int ci = (tb & 15) * 4;
            const float* Wig[3] = {Wri + (size_t)j * F * H, Wui + (size_t)j * F * H,
                                   Wni + (size_t)j * F * H};
#pragma unroll
            for (int g = 0; g < 3; ++g) {
                const f32x4 a = *(const f32x4*)(Wig[g] + (size_t)(2 * p) * H + ci);
                const f32x4 b = *(const f32x4*)(Wig[g] + (size_t)(2 * p + 1) * H + ci);
                uint4 w;
                w.x = pack2(a[0], b[0]); w.y = pack2(a[1], b[1]);
                w.z = pack2(a[2], b[2]); w.w = pack2(a[3], b[3]);
                *(uint4*)&sLu[OFF_WIN + g * WIN_GATE + p * WROW + ci] = w;
            }
        }
#pragma unroll
        for (int it = 0; it < 8; ++it) {
            const int idx = tb + 256 * it;
            const int b = idx & 31, i = idx >> 5;
            sL[FB_OFF_XH + i * 33 + b] = hidden[(size_t)(b * H + i) * L + j];
        }
    }
    __syncthreads();

    const int lane = tb & 63;
    const int n    = tb >> 6;
    const int lc   = lane & 15;
    const int grp  = lane >> 4;
    const int col  = n * 16 + lc;

    bf16x8 aH[2][2], aI[2];
#pragma unroll
    for (int m = 0; m < 2; ++m) {
        const int b_ = m * 16 + lc;
#pragma unroll
        for (int ks = 0; ks < 2; ++ks)
#pragma unroll
            for (int e = 0; e < 8; ++e)
                aH[m][ks][e] = (__bf16)sL[FB_OFF_XH + (ks * 32 + grp * 8 + e) * 33 + b_];
        const size_t ibase = (size_t)b_ * F * L + j;
#pragma unroll
        for (int e = 0; e < 8; ++e) {
            const float v = (grp == 0) ? xin[ibase + (size_t)e * L] : 0.0f;
            aI[m][e] = (__bf16)v;
        }
    }
    __syncthreads();

    const size_t ko = (size_t)col * L + j;
    const float biR  = Brh[ko] + Bri[ko];
    const float biU  = Buh[ko] + Bui[ko];
    const float biNH = Bnh[ko];
    const float biNI = Bni[ko];

    auto rdH = [&](int g, int ks) -> bf16x8 {
        uint4 t;
        t.x = sLu[g * W_GATE + (ks * 16 + grp * 4 + 0) * WROW + col];
        t.y = sLu[g * W_GATE + (ks * 16 + grp * 4 + 1) * WROW + col];
        t.z = sLu[g * W_GATE + (ks * 16 + grp * 4 + 2) * WROW + col];
        t.w = sLu[g * W_GATE + (ks * 16 + grp * 4 + 3) * WROW + col];
        return __builtin_bit_cast(bf16x8, t);
    };
    auto rdI = [&](int g) -> bf16x8 {
        uint4 t;
        t.x = (grp == 0) ? sLu[OFF_WIN + g * WIN_GATE + 0 * WROW + col] : 0u;
        t.y = (grp == 0) ? sLu[OFF_WIN + g * WIN_GATE + 1 * WROW + col] : 0u;
        t.z = (grp == 0) ? sLu[OFF_WIN + g * WIN_GATE + 2 * WROW + col] : 0u;
        t.w = (grp == 0) ? sLu[OFF_WIN + g * WIN_GATE + 3 * WROW + col] : 0u;
        return __builtin_bit_cast(bf16x8, t);
    };

    const bf16x8 fR0 = rdH(0, 0), fR1 = rdH(0, 1);
    const bf16x8 fU0 = rdH(1, 0), fU1 = rdH(1, 1);
    const bf16x8 fN0 = rdH(2, 0), fN1 = rdH(2, 1);
    const bf16x8 fRI = rdI(0), fUI = rdI(1), fNI = rdI(2);

    f32x4 accR[2], accU[2], accN[2], accNI[2];
#pragma unroll
    for (int m = 0; m < 2; ++m) {
        accR[m]  = (f32x4){0.f, 0.f, 0.f, 0.f};
        accU[m]  = (f32x4){0.f, 0.f, 0.f, 0.f};
        accN[m]  = (f32x4){0.f, 0.f, 0.f, 0.f};
        accNI[m] = (f32x4){0.f, 0.f, 0.f, 0.f};
        accR[m] = __builtin_amdgcn_mfma_f32_16x16x32_bf16(aH[m][0], fR0, accR[m], 0, 0, 0);
        accR[m] = __builtin_amdgcn_mfma_f32_16x16x32_bf16(aH[m][1], fR1, accR[m], 0, 0, 0);
        accU[m] = __builtin_amdgcn_mfma_f32_16x16x32_bf16(aH[m][0], fU0, accU[m], 0, 0, 0);
        accU[m] = __builtin_amdgcn_mfma_f32_16x16x32_bf16(aH[m][1], fU1, accU[m], 0, 0, 0);
        accN[m] = __builtin_amdgcn_mfma_f32_16x16x32_bf16(aH[m][0], fN0, accN[m], 0, 0, 0);
        accN[m] = __builtin_amdgcn_mfma_f32_16x16x32_bf16(aH[m][1], fN1, accN[m], 0, 0, 0);
        accR[m]  = __builtin_amdgcn_mfma_f32_16x16x32_bf16(aI[m], fRI, accR[m], 0, 0, 0);
        accU[m]  = __builtin_amdgcn_mfma_f32_16x16x32_bf16(aI[m], fUI, accU[m], 0, 0, 0);
        accNI[m] = __builtin_amdgcn_mfma_f32_16x16x32_bf16(aI[m], fNI, accNI[m], 0, 0, 0);
    }

#pragma unroll
    for (int m = 0; m < 2; ++m)
#pragma unroll
        for (int rr = 0; rr < 4; ++rr) {
            const int b_ = m * 16 + grp * 4 + rr;
            const int w = FB_OFF_XH + col * 33 + b_;
            const float h = sL[w];
            const float rv = fsigmoid(accR[m][rr] + biR);
            const float uv = fsigmoid(accU[m][rr] + biU);
            const float nv = ftanh(rv * (accN[m][rr] + biNH) + accNI[m][rr] + biNI);
            sL[w] = (1.0f - uv) * nv + uv * h;
        }
    __syncthreads();

#pragma unroll
    for (int it = 0; it < 8; ++it) {
        const int idx = tb + 256 * it;
        const int b = idx & 31, k = idx >> 5;
        out[(size_t)(b * H + k) * L + j] = sL[FB_OFF_XH + k * 33 + b];
    }
}

} // namespace

extern "C" void kernel_launch(void* const* d_in, const int* in_sizes, int n_in,
                              void* d_out, int out_size, void* d_ws, size_t ws_size,
                              hipStream_t stream) {
    const float* hidden = (const float*)d_in[0];
    const float* xin    = (const float*)d_in[1];
    const float* Wrh    = (const float*)d_in[2];
    const float* Brh    = (const float*)d_in[3];
    const float* Wri    = (const float*)d_in[4];
    const float* Bri    = (const float*)d_in[5];
    const float* Wuh    = (const float*)d_in[6];
    const float* Buh    = (const float*)d_in[7];
    const float* Wui    = (const float*)d_in[8];
    const float* Bui    = (const float*)d_in[9];
    const float* Wnh    = (const float*)d_in[10];
    const float* Bnh    = (const float*)d_in[11];
    const float* Wni    = (const float*)d_in[12];
    const float* Bni    = (const float*)d_in[13];
    float* out = (float*)d_out;

    if (ws_size >= WS_NEED) {
        char* ws = (char*)d_ws;
        uint4* PA  = (uint4*)(ws + PA_OFF);
        float* PB  = (float*)(ws + PB_OFF);
        uint4* PNU = (uint4*)(ws + PNU_OFF);

        pre_pack<<<(L / 16) * 4, 256, 0, stream>>>(hidden, xin,
                                                   Brh, Bri, Buh, Bui, Bnh, Bni,
                                                   PA, PB);
        gcrnn_main<<<L, 256, 0, stream>>>(PA, PB,
                                          Wrh, Wuh, Wnh, Wri, Wui, Wni,
                                          PNU);
        post_blend<<<(L / 16) * 4, 256, 0, stream>>>(PNU, hidden, out);
    } else {
        gcrnn_fallback<<<L, 256, 0, stream>>>(hidden, xin,
                                              Wrh, Brh, Wri, Bri,
                                              Wuh, Buh, Wui, Bui,
                                              Wnh, Bnh, Wni, Bni,
                                              out);
    }
}